// Round 2
// baseline (216.893 us; speedup 1.0000x reference)
//
#include <hip/hip_runtime.h>

#define Bn 128
#define Dd 32
#define Pp 13
#define Ss 64
#define Ee 16
#define Hh 4
#define HDim 4
#define Ll 416           // Dd*Pp
#define Rr (Bn*Ll)       // 53248 rows

// ---------------------------------------------------------------------------
// Kernel A: fused encoder + QKV. One wave (=block) handles 64 rows.
// Phase 1: lane = hidden unit. w1 column in 66 VGPRs (loaded once), feats via
//          uniform loads (scalar pipe), 64 independent rows -> huge ILP.
//          h staged to LDS at stride 65 (conflict-free both phases).
// Phase 2: lane = row. enc(16) + qkv(48) per-lane, fully unrolled, uniform
//          weight loads, coalesced float4 stores of Q/K/V in (B,H,L,HD).
// Q pre-scaled by 0.5*log2(e) so attention uses raw exp2.
// ---------------------------------------------------------------------------
__global__ __launch_bounds__(64) void enc_qkv_kernel(
    const float* __restrict__ board, const float* __restrict__ w1,
    const float* __restrict__ b1, const float* __restrict__ w2,
    const float* __restrict__ b2, const float* __restrict__ w_qkv,
    const float* __restrict__ b_qkv,
    float* __restrict__ Q, float* __restrict__ K, float* __restrict__ V)
{
    __shared__ float sh[64 * 65];   // h[row_local][hidden], stride 65

    const int t = threadIdx.x;          // lane 0..63
    const int row0 = blockIdx.x * 64;   // 832 blocks exactly cover 53248 rows

    // Preload w1 column t: w[i] = w1[i][t]  (coalesced 256B per i, once/block)
    float w[66];
    #pragma unroll
    for (int i = 0; i < 66; ++i) w[i] = w1[i * 64 + t];
    const float bias1 = b1[t];

    // ---------------- Phase 1: h = relu(feats @ w1 + b1) ----------------
    #pragma unroll 2
    for (int r = 0; r < 64; ++r) {
        const int row = row0 + r;
        const int b = row / Ll;
        const int l = row - b * Ll;
        const int d = l / Pp;
        const int p = l - d * Pp;
        // board[((b*Dd+d)*Pp+p)*64] == board[row*64]
        const float4* brow = (const float4*)(board + (size_t)row * 64);
        float4 f[16];
        #pragma unroll
        for (int c = 0; c < 16; ++c) f[c] = brow[c];
        float acc = bias1;
        #pragma unroll
        for (int c = 0; c < 16; ++c) {
            acc = fmaf(f[c].x, w[4 * c + 0], acc);
            acc = fmaf(f[c].y, w[4 * c + 1], acc);
            acc = fmaf(f[c].z, w[4 * c + 2], acc);
            acc = fmaf(f[c].w, w[4 * c + 3], acc);
        }
        acc = fmaf((float)p, w[64], acc);
        acc = fmaf((float)d, w[65], acc);
        sh[r * 65 + t] = fmaxf(acc, 0.0f);
    }
    __syncthreads();

    // ---------------- Phase 2: lane = row ----------------
    const int row = row0 + t;
    const int b = row / Ll;
    const int l = row - b * Ll;

    float enc[16];
    #pragma unroll
    for (int e = 0; e < 16; ++e) enc[e] = b2[e];

    const float4* w2v = (const float4*)w2;
    #pragma unroll 2
    for (int j = 0; j < 64; ++j) {
        const float hj = sh[t * 65 + j];     // stride-65: conflict-free
        const float4 wa = w2v[j * 4 + 0];
        const float4 wb = w2v[j * 4 + 1];
        const float4 wc = w2v[j * 4 + 2];
        const float4 wd = w2v[j * 4 + 3];
        enc[0]  = fmaf(hj, wa.x, enc[0]);  enc[1]  = fmaf(hj, wa.y, enc[1]);
        enc[2]  = fmaf(hj, wa.z, enc[2]);  enc[3]  = fmaf(hj, wa.w, enc[3]);
        enc[4]  = fmaf(hj, wb.x, enc[4]);  enc[5]  = fmaf(hj, wb.y, enc[5]);
        enc[6]  = fmaf(hj, wb.z, enc[6]);  enc[7]  = fmaf(hj, wb.w, enc[7]);
        enc[8]  = fmaf(hj, wc.x, enc[8]);  enc[9]  = fmaf(hj, wc.y, enc[9]);
        enc[10] = fmaf(hj, wc.z, enc[10]); enc[11] = fmaf(hj, wc.w, enc[11]);
        enc[12] = fmaf(hj, wd.x, enc[12]); enc[13] = fmaf(hj, wd.y, enc[13]);
        enc[14] = fmaf(hj, wd.z, enc[14]); enc[15] = fmaf(hj, wd.w, enc[15]);
    }

    // qkv[j] = b_qkv[j] + enc . w_qkv[j][:]
    float qkv[48];
    #pragma unroll
    for (int j = 0; j < 48; ++j) {
        const float4* wr = (const float4*)(w_qkv + j * 16);
        const float4 x0 = wr[0], x1 = wr[1], x2 = wr[2], x3 = wr[3];
        float a = b_qkv[j];
        a = fmaf(enc[0],  x0.x, a); a = fmaf(enc[1],  x0.y, a);
        a = fmaf(enc[2],  x0.z, a); a = fmaf(enc[3],  x0.w, a);
        a = fmaf(enc[4],  x1.x, a); a = fmaf(enc[5],  x1.y, a);
        a = fmaf(enc[6],  x1.z, a); a = fmaf(enc[7],  x1.w, a);
        a = fmaf(enc[8],  x2.x, a); a = fmaf(enc[9],  x2.y, a);
        a = fmaf(enc[10], x2.z, a); a = fmaf(enc[11], x2.w, a);
        a = fmaf(enc[12], x3.x, a); a = fmaf(enc[13], x3.y, a);
        a = fmaf(enc[14], x3.z, a); a = fmaf(enc[15], x3.w, a);
        qkv[j] = a;
    }

    const float SC = 0.72134752044f;   // 0.5 * log2(e)
    #pragma unroll
    for (int h = 0; h < 4; ++h) {
        const size_t base = (((size_t)(b * Hh + h)) * Ll + l) * HDim;
        *(float4*)(Q + base) = make_float4(qkv[h*4+0]*SC, qkv[h*4+1]*SC,
                                           qkv[h*4+2]*SC, qkv[h*4+3]*SC);
        *(float4*)(K + base) = make_float4(qkv[16+h*4+0], qkv[16+h*4+1],
                                           qkv[16+h*4+2], qkv[16+h*4+3]);
        *(float4*)(V + base) = make_float4(qkv[32+h*4+0], qkv[32+h*4+1],
                                           qkv[32+h*4+2], qkv[32+h*4+3]);
    }
}

// ---------------------------------------------------------------------------
// Kernel B: attention per (b,h). K/V in LDS; 4 q-rows per thread (128-thread
// blocks) to halve LDS instruction issue vs 2 rows / 256 threads.
// Max-free single-pass softmax (scores tiny; softmax shift-invariant).
// ---------------------------------------------------------------------------
__global__ __launch_bounds__(128) void attn_kernel(
    const float* __restrict__ Q, const float* __restrict__ K,
    const float* __restrict__ V, float* __restrict__ ATT)
{
    __shared__ float4 sk[Ll];
    __shared__ float4 sv[Ll];

    const int bh = blockIdx.x;            // b*Hh + h
    const int tid = threadIdx.x;
    const float4* Kb = (const float4*)(K + (size_t)bh * Ll * HDim);
    const float4* Vb = (const float4*)(V + (size_t)bh * Ll * HDim);
    for (int i = tid; i < Ll; i += 128) { sk[i] = Kb[i]; sv[i] = Vb[i]; }
    __syncthreads();

    const float4* Qb = (const float4*)(Q + (size_t)bh * Ll * HDim);
    const bool has3 = (tid + 384 < Ll);   // tid < 32
    float4 q[4];
    #pragma unroll
    for (int j = 0; j < 3; ++j) q[j] = Qb[tid + 128 * j];
    q[3] = has3 ? Qb[tid + 384] : make_float4(0.f, 0.f, 0.f, 0.f);

    float s[4];
    float4 o[4];
    #pragma unroll
    for (int j = 0; j < 4; ++j) { s[j] = 0.f; o[j] = make_float4(0.f,0.f,0.f,0.f); }

    #pragma unroll 2
    for (int l = 0; l < Ll; ++l) {
        const float4 k = sk[l];
        const float4 v = sv[l];
        #pragma unroll
        for (int j = 0; j < 4; ++j) {
            float dot = q[j].x * k.x;
            dot = fmaf(q[j].y, k.y, dot);
            dot = fmaf(q[j].z, k.z, dot);
            dot = fmaf(q[j].w, k.w, dot);
            const float e = __builtin_amdgcn_exp2f(dot);
            s[j] += e;
            o[j].x = fmaf(e, v.x, o[j].x);
            o[j].y = fmaf(e, v.y, o[j].y);
            o[j].z = fmaf(e, v.z, o[j].z);
            o[j].w = fmaf(e, v.w, o[j].w);
        }
    }

    const int b = bh >> 2;
    const int h = bh & 3;
    #pragma unroll
    for (int j = 0; j < 4; ++j) {
        const int qi = tid + 128 * j;
        if (j == 3 && !has3) break;
        const float inv = 1.0f / s[j];
        float4* dst = (float4*)(ATT + ((size_t)(b * Ll + qi)) * Ee + h * HDim);
        *dst = make_float4(o[j].x * inv, o[j].y * inv, o[j].z * inv, o[j].w * inv);
    }
}

// ---------------------------------------------------------------------------
// Kernel C: out projection (unchanged).
// ---------------------------------------------------------------------------
__global__ __launch_bounds__(256) void outproj_kernel(
    const float* __restrict__ ATT, const float* __restrict__ w_out,
    const float* __restrict__ b_out, float* __restrict__ out)
{
    __shared__ float sx[256];
    __shared__ float sw[256];   // sw[e*16+o] = w_out[o*16+e]

    const int tid = threadIdx.x;
    const size_t gbase = (size_t)blockIdx.x * 256;
    sx[tid] = ATT[gbase + tid];
    sw[tid] = w_out[(tid & 15) * 16 + (tid >> 4)];
    __syncthreads();

    const int rloc = tid >> 4;
    const int o = tid & 15;
    float acc = b_out[o];
    #pragma unroll
    for (int e = 0; e < 16; ++e)
        acc = fmaf(sx[rloc * 16 + e], sw[e * 16 + o], acc);
    out[gbase + tid] = acc;
}

// ---------------------------------------------------------------------------
extern "C" void kernel_launch(void* const* d_in, const int* in_sizes, int n_in,
                              void* d_out, int out_size, void* d_ws, size_t ws_size,
                              hipStream_t stream) {
    const float* board = (const float*)d_in[0];
    const float* w1    = (const float*)d_in[1];
    const float* b1    = (const float*)d_in[2];
    const float* w2    = (const float*)d_in[3];
    const float* b2    = (const float*)d_in[4];
    const float* w_qkv = (const float*)d_in[5];
    const float* b_qkv = (const float*)d_in[6];
    const float* w_out = (const float*)d_in[7];
    const float* b_out = (const float*)d_in[8];
    float* out = (float*)d_out;

    float* ws  = (float*)d_ws;
    float* Q   = ws;                        // (B,H,L,HD)
    float* K   = ws + (size_t)Rr * Ee;
    float* V   = ws + (size_t)2 * Rr * Ee;
    float* ATT = ws + (size_t)3 * Rr * Ee;  // (B,L,E)

    hipLaunchKernelGGL(enc_qkv_kernel, dim3(Rr / 64), dim3(64), 0, stream,
                       board, w1, b1, w2, b2, w_qkv, b_qkv, Q, K, V);
    hipLaunchKernelGGL(attn_kernel, dim3(Bn * Hh), dim3(128), 0, stream,
                       Q, K, V, ATT);
    hipLaunchKernelGGL(outproj_kernel, dim3((Rr * Ee) / 256), dim3(256), 0, stream,
                       ATT, w_out, b_out, out);
}